// Round 1
// baseline (9574.586 us; speedup 1.0000x reference)
//
#include <hip/hip_runtime.h>

#define HH 20          // hidden size
#define HHALF 10       // units per wave (2-wave split)
#define TSTEPS 256
#define FF 64
#define EPB 64         // batch elements per block
#define BLK 128        // 2 waves

typedef __attribute__((ext_vector_type(2))) _Float16 h2f;

__device__ __forceinline__ h2f asH2(unsigned int w) {
    return __builtin_bit_cast(h2f, w);
}

#if __has_builtin(__builtin_amdgcn_fdot2)
__device__ __forceinline__ float fdot2(h2f a, h2f b, float c) {
    return __builtin_amdgcn_fdot2(a, b, c, false);   // v_dot2_f32_f16
}
#else
__device__ __forceinline__ float fdot2(h2f a, h2f b, float c) {
    return fmaf((float)a.y, (float)b.y, fmaf((float)a.x, (float)b.x, c));
}
#endif

__device__ __forceinline__ float fast_sigm(float x) {
    float e = __expf(-x);
    return __builtin_amdgcn_rcpf(1.0f + e);          // rcp(inf)=0, safe
}
__device__ __forceinline__ float fast_tanh(float x) {
    float e = __expf(2.0f * x);                      // inf => 1, 0 => -1, no overflow
    return 1.0f - 2.0f * __builtin_amdgcn_rcpf(1.0f + e);
}

__device__ __forceinline__ unsigned int packf16(float a, float b) {
    unsigned short ua = __builtin_bit_cast(unsigned short, (_Float16)a);  // RNE cvt
    unsigned short ub = __builtin_bit_cast(unsigned short, (_Float16)b);
    return (unsigned int)ua | ((unsigned int)ub << 16);
}

// ---------------------------------------------------------------------------
// Workspace layout (uint index):
//   [0..79]       bs1  fp32  bias sums layer1, order [u*4+g], g in {i,f,g,o}
//   [80..159]     wx1  fp32  Wih1 reordered [u*4+g]
//   [160..239]    bs2  fp32  bias sums layer2 [u*4+g]
//   [240..1039]   pk1  [20u][4g][10] packed f16 pairs of Whh1 rows
//   [1040..2639]  pk2  [20u][4g][ vi(10) | wi(10) ] packed f16 (Wih2 | Whh2)
// Total 2640 u32 = 10560 B.
// ---------------------------------------------------------------------------
__global__ void prep_weights(
    const float* __restrict__ Wih1, const float* __restrict__ Whh1,
    const float* __restrict__ bih1, const float* __restrict__ bhh1,
    const float* __restrict__ Wih2, const float* __restrict__ Whh2,
    const float* __restrict__ bih2, const float* __restrict__ bhh2,
    unsigned int* __restrict__ ws)
{
    const int t = blockIdx.x * blockDim.x + threadIdx.x;
    const int stride = blockDim.x * gridDim.x;
    float* wsf = (float*)ws;
    for (int i = t; i < 80; i += stride) {
        int u = i >> 2, g = i & 3, r = g * HH + u;
        wsf[i]       = bih1[r] + bhh1[r];
        wsf[80 + i]  = Wih1[r];              // in_dim = 1
        wsf[160 + i] = bih2[r] + bhh2[r];
    }
    for (int i = t; i < 800; i += stride) {  // pk1
        int k = i % 10, g = (i / 10) & 3, u = i / 40;
        int r = g * HH + u;
        ws[240 + i] = packf16(Whh1[r * HH + 2 * k], Whh1[r * HH + 2 * k + 1]);
    }
    for (int i = t; i < 1600; i += stride) { // pk2
        int j = i % 20, g = (i / 20) & 3, u = i / 80;
        int r = g * HH + u;
        unsigned int v;
        if (j < 10) v = packf16(Wih2[r * HH + 2 * j],        Wih2[r * HH + 2 * j + 1]);
        else        v = packf16(Whh2[r * HH + 2 * (j - 10)], Whh2[r * HH + 2 * (j - 10) + 1]);
        ws[1040 + i] = v;
    }
}

// ---------------------------------------------------------------------------
// 2 waves per 64-element group. Wave `half` owns units [half*10, half*10+10)
// of BOTH layers (u stays wave-uniform -> weight loads stay scalar s_loads).
// h state carried as packed fp16 in registers; exchanged through fp16 LDS
// rows [elem][22] (stride 11 dwords, coprime with 32 banks -> conflict-free).
// c state fp32 in LDS, wave-private. 2 barriers per timestep.
// ---------------------------------------------------------------------------
__global__ __launch_bounds__(BLK, 4) void lstm_fused(
    const float* __restrict__ diag,
    const unsigned int* __restrict__ ws,
    const float* __restrict__ W1, const float* __restrict__ b1,   // [64][20],[64]
    const float* __restrict__ W2, const float* __restrict__ b2,   // [64],[1]
    float* __restrict__ out, int Btot)
{
    __shared__ float s_c1[HH][EPB];                       // 5120 B
    __shared__ float s_c2[HH][EPB];                       // 5120 B
    __shared__ __attribute__((aligned(4))) unsigned short s_hA[EPB][22];  // 2816 B
    __shared__ __attribute__((aligned(4))) unsigned short s_hB[EPB][22];  // 2816 B

    const int tid   = threadIdx.x;
    const int lane  = tid & 63;
    const int half  = tid >> 6;                 // 0 or 1
    const int ubase = half * HHALF;
    const int e     = blockIdx.x * EPB + lane;  // batch element

    // init wave-private cell state
    #pragma unroll
    for (int uu = 0; uu < HHALF; ++uu) {
        s_c1[ubase + uu][lane] = 0.0f;
        s_c2[ubase + uu][lane] = 0.0f;
    }

    h2f h1p[10], h2p[10];                       // full h (20 vals) packed
    #pragma unroll
    for (int k = 0; k < 10; ++k) { h1p[k] = asH2(0u); h2p[k] = asH2(0u); }

    const int esafe = (e < Btot) ? e : (Btot - 1);
    const float* __restrict__ xr = diag + (long long)esafe * TSTEPS;
    float x = xr[0];

    const float* bs1 = (const float*)ws;
    const float* wx1 = (const float*)ws + 80;
    const float* bs2 = (const float*)ws + 160;
    const unsigned int* pk1 = ws + 240;
    const unsigned int* pk2 = ws + 1040;

    #pragma unroll 1
    for (int t = 0; t < TSTEPS; ++t) {
        float xnext = xr[(t + 1) & (TSTEPS - 1)];   // prefetch (wraps, unused at end)

        // ================= layer 1 : this wave's 10 units =================
        #pragma unroll 1
        for (int uu = 0; uu < HHALF; ++uu) {
            const int u = ubase + uu;
            const unsigned int* __restrict__ wr = pk1 + u * 40;
            const float* __restrict__ bb = bs1 + u * 4;
            const float* __restrict__ wx = wx1 + u * 4;
            float zi = fmaf(x, wx[0], bb[0]);
            float zf = fmaf(x, wx[1], bb[1]);
            float zg = fmaf(x, wx[2], bb[2]);
            float zo = fmaf(x, wx[3], bb[3]);
            #pragma unroll
            for (int k = 0; k < 10; ++k) {
                h2f hk = h1p[k];
                zi = fdot2(hk, asH2(wr[k]),      zi);
                zf = fdot2(hk, asH2(wr[10 + k]), zf);
                zg = fdot2(hk, asH2(wr[20 + k]), zg);
                zo = fdot2(hk, asH2(wr[30 + k]), zo);
            }
            float c  = s_c1[u][lane];
            float cn = fast_sigm(zf) * c + fast_sigm(zi) * fast_tanh(zg);
            s_c1[u][lane] = cn;
            float hn = fast_sigm(zo) * fast_tanh(cn);
            s_hA[lane][u] = __builtin_bit_cast(unsigned short, (_Float16)hn);
        }
        __syncthreads();   // drains LDS; publishes both halves of h1'

        h2f h1n[10];
        {
            const unsigned int* __restrict__ hrow = (const unsigned int*)&s_hA[lane][0];
            #pragma unroll
            for (int k = 0; k < 10; ++k) h1n[k] = asH2(hrow[k]);
        }

        // ================= layer 2 : this wave's 10 units =================
        #pragma unroll 1
        for (int uu = 0; uu < HHALF; ++uu) {
            const int u = ubase + uu;
            const unsigned int* __restrict__ wr = pk2 + u * 80;
            const float* __restrict__ bb = bs2 + u * 4;
            float zi = bb[0], zf = bb[1], zg = bb[2], zo = bb[3];
            #pragma unroll
            for (int k = 0; k < 10; ++k) {          // input part: h1'
                h2f ak = h1n[k];
                zi = fdot2(ak, asH2(wr[k]),      zi);
                zf = fdot2(ak, asH2(wr[20 + k]), zf);
                zg = fdot2(ak, asH2(wr[40 + k]), zg);
                zo = fdot2(ak, asH2(wr[60 + k]), zo);
            }
            #pragma unroll
            for (int k = 0; k < 10; ++k) {          // recurrent part: h2
                h2f bk = h2p[k];
                zi = fdot2(bk, asH2(wr[10 + k]), zi);
                zf = fdot2(bk, asH2(wr[30 + k]), zf);
                zg = fdot2(bk, asH2(wr[50 + k]), zg);
                zo = fdot2(bk, asH2(wr[70 + k]), zo);
            }
            float c  = s_c2[u][lane];
            float cn = fast_sigm(zf) * c + fast_sigm(zi) * fast_tanh(zg);
            s_c2[u][lane] = cn;
            float hn = fast_sigm(zo) * fast_tanh(cn);
            s_hB[lane][u] = __builtin_bit_cast(unsigned short, (_Float16)hn);
        }
        __syncthreads();   // publishes both halves of h2'

        {
            const unsigned int* __restrict__ hrow = (const unsigned int*)&s_hB[lane][0];
            #pragma unroll
            for (int k = 0; k < 10; ++k) h2p[k] = asH2(hrow[k]);
        }
        #pragma unroll
        for (int k = 0; k < 10; ++k) h1p[k] = h1n[k];

        x = xnext;
    }

    // ---- head (fp32, wave 0 only): relu(h2 @ W1^T + b1) @ W2^T + b2 ----
    if (half == 0 && e < Btot) {
        float hv[HH];
        #pragma unroll
        for (int k = 0; k < 10; ++k) {
            h2f p = h2p[k];
            hv[2 * k]     = (float)p.x;
            hv[2 * k + 1] = (float)p.y;
        }
        float y2 = b2[0];
        #pragma unroll 1
        for (int j = 0; j < FF; ++j) {
            float a = b1[j];
            const float* __restrict__ wj = W1 + j * HH;
            #pragma unroll
            for (int k = 0; k < HH; ++k) a = fmaf(hv[k], wj[k], a);
            a = fmaxf(a, 0.0f);
            y2 = fmaf(a, W2[j], y2);
        }
        out[e] = fmaxf(y2, 0.0f);
    }
}

extern "C" void kernel_launch(void* const* d_in, const int* in_sizes, int n_in,
                              void* d_out, int out_size, void* d_ws, size_t ws_size,
                              hipStream_t stream)
{
    (void)n_in; (void)ws_size; (void)out_size;
    const float* diag = (const float*)d_in[0];
    const float* Wih1 = (const float*)d_in[1];
    const float* Whh1 = (const float*)d_in[2];
    const float* bih1 = (const float*)d_in[3];
    const float* bhh1 = (const float*)d_in[4];
    const float* Wih2 = (const float*)d_in[5];
    const float* Whh2 = (const float*)d_in[6];
    const float* bih2 = (const float*)d_in[7];
    const float* bhh2 = (const float*)d_in[8];
    const float* W1   = (const float*)d_in[9];
    const float* b1   = (const float*)d_in[10];
    const float* W2   = (const float*)d_in[11];
    const float* b2   = (const float*)d_in[12];

    const int Btot = in_sizes[0] / TSTEPS;   // 131072
    unsigned int* ws = (unsigned int*)d_ws;

    prep_weights<<<1, 256, 0, stream>>>(Wih1, Whh1, bih1, bhh1,
                                        Wih2, Whh2, bih2, bhh2, ws);

    lstm_fused<<<(Btot + EPB - 1) / EPB, BLK, 0, stream>>>(
        diag, ws, W1, b1, W2, b2, (float*)d_out, Btot);
}

// Round 2
// 1703.366 us; speedup vs baseline: 5.6210x; 5.6210x over previous
//
#include <hip/hip_runtime.h>

#define HH 20
#define TSTEPS 256
#define FF 64
#define ROWLEN 72          // f16 per LDS row (144 B, 16B-aligned, 36-dword stride)

typedef __attribute__((ext_vector_type(8))) _Float16 f16x8;
typedef __attribute__((ext_vector_type(2))) _Float16 f16x2;
typedef __attribute__((ext_vector_type(4))) float    f32x4;

__device__ __forceinline__ f32x4 mfma16(f16x8 a, f16x8 b, f32x4 c) {
    return __builtin_amdgcn_mfma_f32_16x16x32_f16(a, b, c, 0, 0, 0);
}

__device__ __forceinline__ float fast_sigm(float x) {
    float e = __expf(-x);
    return __builtin_amdgcn_rcpf(1.0f + e);          // rcp(inf)=0, safe
}
__device__ __forceinline__ float fast_tanh(float x) {
    float e = __expf(2.0f * x);                      // inf => 1, 0 => -1, no overflow
    return 1.0f - 2.0f * __builtin_amdgcn_rcpf(1.0f + e);
}

// ---------------------------------------------------------------------------
// Packed augmented weight matrices, f16, row-major, rows r = 4u + g
// (g in {0:i,1:f,2:g,3:o}; original row ro = g*20 + u).
//
//   W1c [80][32]:  k 0..19 = Whh1[ro][k]   (h1 recurrence)
//                  k 20    = Wih1[ro]      (x column)
//                  k 21    = bih1+bhh1[ro] (bias, paired with constant 1.0)
//                  k 22..31 = 0            (h2 region of the shared B rows)
//   W2c [80][64]:  k 0..19 = Wih2[ro][k]   (h1 input)
//                  k 20    = 0             (x column unused by layer 2)
//                  k 21    = bih2+bhh2[ro] (bias via same 1.0 column)
//                  k 22..41 = Whh2[ro][k-22] (h2 recurrence)
//                  k 42..63 = 0
//
// Shared per-batch B row in LDS (f16[72]):
//   [0..19]=h1, [20]=x, [21]=1.0, [22..41]=h2, [42..71]=0 (never written)
// ---------------------------------------------------------------------------
__global__ void prep_weights(
    const float* __restrict__ Wih1, const float* __restrict__ Whh1,
    const float* __restrict__ bih1, const float* __restrict__ bhh1,
    const float* __restrict__ Wih2, const float* __restrict__ Whh2,
    const float* __restrict__ bih2, const float* __restrict__ bhh2,
    _Float16* __restrict__ ws)
{
    const int t0 = blockIdx.x * blockDim.x + threadIdx.x;
    const int stride = blockDim.x * gridDim.x;
    for (int idx = t0; idx < 80 * 32; idx += stride) {
        int r = idx >> 5, k = idx & 31;
        int u = r >> 2, g = r & 3, ro = g * HH + u;
        float v = 0.0f;
        if (k < 20)       v = Whh1[ro * HH + k];
        else if (k == 20) v = Wih1[ro];
        else if (k == 21) v = bih1[ro] + bhh1[ro];
        ws[idx] = (_Float16)v;
    }
    for (int idx = t0; idx < 80 * 64; idx += stride) {
        int r = idx >> 6, k = idx & 63;
        int u = r >> 2, g = r & 3, ro = g * HH + u;
        float v = 0.0f;
        if (k < 20)                  v = Wih2[ro * HH + k];
        else if (k == 21)            v = bih2[ro] + bhh2[ro];
        else if (k >= 22 && k < 42)  v = Whh2[ro * HH + (k - 22)];
        ws[2560 + idx] = (_Float16)v;
    }
}

// ---------------------------------------------------------------------------
// One wave per block, 64 batch elements per wave, weights stationary in VGPRs.
// Per step: 20 MFMA (layer1, K-tile0 incl x+bias) + 40 MFMA (layer2, 2 K-tiles),
// lane-local activations (C/D layout: col=lane&15, row=(lane>>4)*4+reg, so the
// 4 gates of unit u=4m+q land in acc regs 0..3 of one lane), c-state in VGPRs.
// No barriers; same-wave DS program order gives h1 -> layer2 hand-off.
// ---------------------------------------------------------------------------
__global__ __launch_bounds__(64, 2) void lstm_mfma(
    const float* __restrict__ diag,
    const _Float16* __restrict__ wpk,
    const float* __restrict__ W1, const float* __restrict__ b1,
    const float* __restrict__ W2, const float* __restrict__ b2,
    float* __restrict__ out, int Btot)
{
    __shared__ _Float16 s_B[64 * ROWLEN];     // 9216 B

    const int lane = threadIdx.x;             // 0..63
    const int q  = lane >> 4;                 // k-group / row-quad group
    const int cc = lane & 15;                 // column within 16-wide tile
    const int e  = blockIdx.x * 64 + lane;
    const int esafe = (e < Btot) ? e : (Btot - 1);

    // zero this lane's B row (covers the padding that is never written)
    {
        uint4 zz = {0u, 0u, 0u, 0u};
        #pragma unroll
        for (int j = 0; j < 9; ++j)
            *(uint4*)(s_B + lane * ROWLEN + j * 8) = zz;
    }

    // stationary A-fragments: row = 16m + cc, k = q*8 + 0..7
    f16x8 A1[5], A2a[5], A2b[5];
    {
        const _Float16* W2c = wpk + 2560;
        const int kb = q * 8;
        #pragma unroll
        for (int m = 0; m < 5; ++m) {
            const int r = 16 * m + cc;
            A1[m]  = *(const f16x8*)(wpk + r * 32 + kb);
            A2a[m] = *(const f16x8*)(W2c + r * 64 + kb);
            A2b[m] = *(const f16x8*)(W2c + r * 64 + 32 + kb);
        }
    }

    float c1[5][4], c2[5][4];
    #pragma unroll
    for (int m = 0; m < 5; ++m)
        #pragma unroll
        for (int n = 0; n < 4; ++n) { c1[m][n] = 0.0f; c2[m][n] = 0.0f; }

    const float* __restrict__ xr = diag + (long long)esafe * TSTEPS;
    float x = xr[0];
    const f32x4 z4 = {0.0f, 0.0f, 0.0f, 0.0f};

    _Float16* __restrict__ wb1 = s_B + cc * ROWLEN + q;        // h1 writes: +n*1152 +4m
    _Float16* __restrict__ wb2 = wb1 + 22;                     // h2 writes
    const _Float16* __restrict__ rbB = s_B + cc * ROWLEN + q * 8; // B-frag reads

    #pragma unroll 1
    for (int t = 0; t < TSTEPS; ++t) {
        float xn = xr[(t + 1) & (TSTEPS - 1)];   // prefetch (wraps, unused at end)

        // publish x(t) and the bias-carrier 1.0 at k=20,21 of own row
        {
            f16x2 pk;
            pk.x = (_Float16)x;
            pk.y = (_Float16)1.0f;
            *(f16x2*)(s_B + lane * ROWLEN + 20) = pk;
        }

        f32x4 z[5][4];

        // ---------------- layer 1: z1 = W1c @ [h1; x; 1; *] ----------------
        #pragma unroll
        for (int n = 0; n < 4; ++n) {
            f16x8 bf = *(const f16x8*)(rbB + n * 16 * ROWLEN);
            #pragma unroll
            for (int m = 0; m < 5; ++m)
                z[m][n] = mfma16(A1[m], bf, z4);
        }
        #pragma unroll
        for (int n = 0; n < 4; ++n) {
            #pragma unroll
            for (int m = 0; m < 5; ++m) {
                f32x4 a = z[m][n];                    // regs: i,f,g,o of unit 4m+q
                float cn = fast_sigm(a.y) * c1[m][n] + fast_sigm(a.x) * fast_tanh(a.z);
                c1[m][n] = cn;
                float hn = fast_sigm(a.w) * fast_tanh(cn);
                wb1[n * 16 * ROWLEN + 4 * m] = (_Float16)hn;   // h1'(t)
            }
        }

        // ---------------- layer 2: z2 = W2c @ [h1'; 0; 1; h2] ----------------
        #pragma unroll
        for (int n = 0; n < 4; ++n) {
            const _Float16* rp = rbB + n * 16 * ROWLEN;
            f16x8 b0 = *(const f16x8*)(rp);           // k 0..31 (h1' + x + 1 + h2lo)
            f16x8 b1f = *(const f16x8*)(rp + 32);     // k 32..63 (h2hi + zeros)
            #pragma unroll
            for (int m = 0; m < 5; ++m)
                z[m][n] = mfma16(A2b[m], b1f, mfma16(A2a[m], b0, z4));
        }
        #pragma unroll
        for (int n = 0; n < 4; ++n) {
            #pragma unroll
            for (int m = 0; m < 5; ++m) {
                f32x4 a = z[m][n];
                float cn = fast_sigm(a.y) * c2[m][n] + fast_sigm(a.x) * fast_tanh(a.z);
                c2[m][n] = cn;
                float hn = fast_sigm(a.w) * fast_tanh(cn);
                wb2[n * 16 * ROWLEN + 4 * m] = (_Float16)hn;   // h2'(t)
            }
        }

        x = xn;
    }

    // ---- head: relu(relu(h2 @ W1^T + b1) @ W2^T + b2), fp32, own element ----
    float hv[HH];
    #pragma unroll
    for (int j = 0; j < HH; ++j)
        hv[j] = (float)s_B[lane * ROWLEN + 22 + j];

    if (e < Btot) {
        float y2 = b2[0];
        #pragma unroll 1
        for (int jj = 0; jj < FF; ++jj) {
            float a = b1[jj];
            const float* __restrict__ wj = W1 + jj * HH;
            #pragma unroll
            for (int k = 0; k < HH; ++k)
                a = fmaf(hv[k], wj[k], a);
            a = fmaxf(a, 0.0f);
            y2 = fmaf(a, W2[jj], y2);
        }
        out[e] = fmaxf(y2, 0.0f);
    }
}

extern "C" void kernel_launch(void* const* d_in, const int* in_sizes, int n_in,
                              void* d_out, int out_size, void* d_ws, size_t ws_size,
                              hipStream_t stream)
{
    (void)n_in; (void)ws_size; (void)out_size;
    const float* diag = (const float*)d_in[0];
    const float* Wih1 = (const float*)d_in[1];
    const float* Whh1 = (const float*)d_in[2];
    const float* bih1 = (const float*)d_in[3];
    const float* bhh1 = (const float*)d_in[4];
    const float* Wih2 = (const float*)d_in[5];
    const float* Whh2 = (const float*)d_in[6];
    const float* bih2 = (const float*)d_in[7];
    const float* bhh2 = (const float*)d_in[8];
    const float* W1   = (const float*)d_in[9];
    const float* b1   = (const float*)d_in[10];
    const float* W2   = (const float*)d_in[11];
    const float* b2   = (const float*)d_in[12];

    const int Btot = in_sizes[0] / TSTEPS;   // 131072
    _Float16* wpk = (_Float16*)d_ws;

    prep_weights<<<8, 256, 0, stream>>>(Wih1, Whh1, bih1, bhh1,
                                        Wih2, Whh2, bih2, bhh2, wpk);

    lstm_mfma<<<(Btot + 63) / 64, 64, 0, stream>>>(
        diag, wpk, W1, b1, W2, b2, (float*)d_out, Btot);
}

// Round 3
// 1317.118 us; speedup vs baseline: 7.2693x; 1.2933x over previous
//
#include <hip/hip_runtime.h>

#define HH 20
#define TSTEPS 256
#define FF 64
#define EPW 64             // batch elements per wave (1 wave per block)
#define ROWLEN 72          // f16 per LDS B-row; 144 B stride (16B-aligned)
#define LOG2E 1.44269504088896f
// B-row layout (f16 idx): [0..23] h1, 6-stride (lane q writes 6q..6q+4, 6q+5 pad)
//   [24]=x, [25]=1.0 (bias carrier), [26..49] h2 (same 6-stride), [50..71] zero

typedef __attribute__((ext_vector_type(8))) _Float16 f16x8;
typedef __attribute__((ext_vector_type(2))) _Float16 f16x2;
typedef __attribute__((ext_vector_type(4))) float    f32x4;
typedef __attribute__((ext_vector_type(2))) float    f32x2;

__device__ __forceinline__ f32x4 mfma16(f16x8 a, f16x8 b, f32x4 c) {
    return __builtin_amdgcn_mfma_f32_16x16x32_f16(a, b, c, 0, 0, 0);
}
__device__ __forceinline__ float rcpf(float x) { return __builtin_amdgcn_rcpf(x); }
__device__ __forceinline__ float exp2fast(float x) {
#if __has_builtin(__builtin_amdgcn_exp2f)
    return __builtin_amdgcn_exp2f(x);          // v_exp_f32: 2^x native
#else
    return __expf(x * 0.6931471805599453f);
#endif
}

// Gate quads arrive pre-scaled: si=-log2e*zi, sf=-log2e*zf, sg=2log2e*zg, so=-log2e*zo.
// sigma(z)=rcp(1+2^s); sigma(i)tanh(g)=(eg-1)*rcp((1+ei)(1+eg)); h=(ec-1)*rcp((1+eo)(1+ec)).
__device__ __forceinline__ f32x2 act_pair(f32x4 za, f32x4 zb, f32x2& c) {
    f32x2 ei; ei.x = exp2fast(za.x); ei.y = exp2fast(zb.x);
    f32x2 ef; ef.x = exp2fast(za.y); ef.y = exp2fast(zb.y);
    f32x2 eg; eg.x = exp2fast(za.z); eg.y = exp2fast(zb.z);
    f32x2 eo; eo.x = exp2fast(za.w); eo.y = exp2fast(zb.w);
    const f32x2 one = {1.0f, 1.0f};
    f32x2 rf; rf.x = rcpf(1.0f + ef.x); rf.y = rcpf(1.0f + ef.y);
    f32x2 den1 = (one + ei) * (one + eg);
    f32x2 r1; r1.x = rcpf(den1.x); r1.y = rcpf(den1.y);
    c = c * rf + (eg - one) * r1;
    f32x2 sc = c * (2.0f * LOG2E);
    sc.x = fminf(sc.x, 100.0f); sc.y = fminf(sc.y, 100.0f);   // inf*0 NaN guard
    f32x2 ec; ec.x = exp2fast(sc.x); ec.y = exp2fast(sc.y);
    f32x2 den2 = (one + eo) * (one + ec);
    f32x2 r2; r2.x = rcpf(den2.x); r2.y = rcpf(den2.y);
    return (ec - one) * r2;
}
__device__ __forceinline__ float act_one(f32x4 za, float& c) {
    float ei = exp2fast(za.x), ef = exp2fast(za.y);
    float eg = exp2fast(za.z), eo = exp2fast(za.w);
    float rf = rcpf(1.0f + ef);
    float r1 = rcpf((1.0f + ei) * (1.0f + eg));
    c = c * rf + (eg - 1.0f) * r1;
    float sc = fminf(c * (2.0f * LOG2E), 100.0f);
    float ec = exp2fast(sc);
    float r2 = rcpf((1.0f + eo) * (1.0f + ec));
    return (ec - 1.0f) * r2;
}

// ---------------------------------------------------------------------------
// Packed augmented weights, f16, PRE-SCALED by the exp2 gate factors.
// Matrix row r (0..79): m=r>>4, q=(r>>2)&3, g=r&3 -> unit u=5q+m, gate g
// (orig row ro = g*20+u). Column k follows the B-row layout above.
//   W1c [80][32] at ws[0..2559]; W2c [80][64] at ws[2560..7679].
// ---------------------------------------------------------------------------
__global__ void prep_weights(
    const float* __restrict__ Wih1, const float* __restrict__ Whh1,
    const float* __restrict__ bih1, const float* __restrict__ bhh1,
    const float* __restrict__ Wih2, const float* __restrict__ Whh2,
    const float* __restrict__ bih2, const float* __restrict__ bhh2,
    _Float16* __restrict__ ws)
{
    const int t0 = blockIdx.x * blockDim.x + threadIdx.x;
    const int stride = blockDim.x * gridDim.x;
    for (int idx = t0; idx < 80 * 32; idx += stride) {
        int r = idx >> 5, k = idx & 31;
        int m = r >> 4, q = (r >> 2) & 3, g = r & 3;
        int u = 5 * q + m, ro = g * HH + u;
        float s = (g == 2) ? 2.0f * LOG2E : -LOG2E;
        float v = 0.0f;
        if (k < 24)       { int qc = k / 6, wc = k % 6; if (wc < 5) v = Whh1[ro * HH + 5 * qc + wc]; }
        else if (k == 24)   v = Wih1[ro];
        else if (k == 25)   v = bih1[ro] + bhh1[ro];
        ws[idx] = (_Float16)(s * v);
    }
    for (int idx = t0; idx < 80 * 64; idx += stride) {
        int r = idx >> 6, k = idx & 63;
        int m = r >> 4, q = (r >> 2) & 3, g = r & 3;
        int u = 5 * q + m, ro = g * HH + u;
        float s = (g == 2) ? 2.0f * LOG2E : -LOG2E;
        float v = 0.0f;
        if (k < 24)       { int qc = k / 6, wc = k % 6; if (wc < 5) v = Wih2[ro * HH + 5 * qc + wc]; }
        else if (k == 25)   v = bih2[ro] + bhh2[ro];
        else if (k >= 26 && k < 50) {
            int cH = k - 26, qc = cH / 6, wc = cH % 6;
            if (wc < 5) v = Whh2[ro * HH + 5 * qc + wc];
        }
        ws[2560 + idx] = (_Float16)(s * v);
    }
}

// ---------------------------------------------------------------------------
// One wave per block, 64 elements, weights stationary in VGPRs, c in VGPRs.
// Lane (q=lane>>4, cc=lane&15): owns units {5q..5q+4}; h-writes are
// 2x ds_write_b32 + 1x ds_write_b16 at bank (4cc+3q)%32 -> 2-way (free).
// B-frag reads keep the conflict-free (4cc+4q) start-bank pattern.
// ---------------------------------------------------------------------------
__global__ __launch_bounds__(64, 2) void lstm_mfma(
    const float* __restrict__ diag,
    const _Float16* __restrict__ wpk,
    const float* __restrict__ W1, const float* __restrict__ b1,
    const float* __restrict__ W2, const float* __restrict__ b2,
    float* __restrict__ out, int Btot)
{
    __shared__ _Float16 s_B[EPW * ROWLEN];     // 9216 B

    const int lane = threadIdx.x;              // 0..63
    const int q  = lane >> 4;
    const int cc = lane & 15;
    const int e  = blockIdx.x * EPW + lane;
    const int esafe = (e < Btot) ? e : (Btot - 1);

    // zero own B-row (144 B = 9 x uint4)
    {
        uint4 zz = {0u, 0u, 0u, 0u};
        #pragma unroll
        for (int j = 0; j < 9; ++j)
            *(uint4*)((char*)s_B + lane * 144 + j * 16) = zz;
    }

    // stationary A-fragments: lane supplies A[row=16m+cc][k=8q..8q+7]
    f16x8 A1[5], A2a[5], A2b[5];
    {
        const _Float16* W2c = wpk + 2560;
        const int kb = q * 8;
        #pragma unroll
        for (int m = 0; m < 5; ++m) {
            const int r = 16 * m + cc;
            A1[m]  = *(const f16x8*)(wpk + r * 32 + kb);
            A2a[m] = *(const f16x8*)(W2c + r * 64 + kb);
            A2b[m] = *(const f16x8*)(W2c + r * 64 + 32 + kb);
        }
    }

    // cell state: per n-block, 2 packed pairs + 1 scalar per layer
    f32x2 c1p[4][2], c2p[4][2];
    float c1s[4], c2s[4];
    #pragma unroll
    for (int n = 0; n < 4; ++n) {
        c1p[n][0] = (f32x2){0.0f, 0.0f}; c1p[n][1] = (f32x2){0.0f, 0.0f};
        c2p[n][0] = (f32x2){0.0f, 0.0f}; c2p[n][1] = (f32x2){0.0f, 0.0f};
        c1s[n] = 0.0f; c2s[n] = 0.0f;
    }

    const float* __restrict__ xr = diag + (long long)esafe * TSTEPS;
    float x = xr[0];
    const f32x4 zz4 = {0.0f, 0.0f, 0.0f, 0.0f};

    #pragma unroll 1
    for (int t = 0; t < TSTEPS; ++t) {
        float xn = xr[(t + 1) & (TSTEPS - 1)];   // prefetch (wraps; unused at end)

        // publish x(t) and the 1.0 bias carrier at k=24,25 of own row
        {
            f16x2 pk; pk.x = (_Float16)x; pk.y = (_Float16)1.0f;
            *(f16x2*)(s_B + lane * ROWLEN + 24) = pk;
        }

        // ================= layer 1 =================
        #pragma unroll
        for (int n = 0; n < 4; ++n) {
            const _Float16* rowp = s_B + (n * 16 + cc) * ROWLEN;
            f16x8 bf = *(const f16x8*)(rowp + 8 * q);
            f32x4 z0 = mfma16(A1[0], bf, zz4);
            f32x4 z1 = mfma16(A1[1], bf, zz4);
            f32x4 z2 = mfma16(A1[2], bf, zz4);
            f32x4 z3 = mfma16(A1[3], bf, zz4);
            f32x4 z4 = mfma16(A1[4], bf, zz4);
            _Float16* wp = s_B + (n * 16 + cc) * ROWLEN + 6 * q;
            f32x2 h01 = act_pair(z0, z1, c1p[n][0]);
            { f16x2 o; o.x = (_Float16)h01.x; o.y = (_Float16)h01.y; *(f16x2*)(wp) = o; }
            f32x2 h23 = act_pair(z2, z3, c1p[n][1]);
            { f16x2 o; o.x = (_Float16)h23.x; o.y = (_Float16)h23.y; *(f16x2*)(wp + 2) = o; }
            float h4 = act_one(z4, c1s[n]);
            wp[4] = (_Float16)h4;
        }

        // ================= layer 2 =================
        #pragma unroll
        for (int n = 0; n < 4; ++n) {
            const _Float16* rowp = s_B + (n * 16 + cc) * ROWLEN;
            f16x8 b0  = *(const f16x8*)(rowp + 8 * q);        // k 0..31
            f16x8 b1f = *(const f16x8*)(rowp + 32 + 8 * q);   // k 32..63
            f32x4 z0 = mfma16(A2b[0], b1f, mfma16(A2a[0], b0, zz4));
            f32x4 z1 = mfma16(A2b[1], b1f, mfma16(A2a[1], b0, zz4));
            f32x4 z2 = mfma16(A2b[2], b1f, mfma16(A2a[2], b0, zz4));
            f32x4 z3 = mfma16(A2b[3], b1f, mfma16(A2a[3], b0, zz4));
            f32x4 z4 = mfma16(A2b[4], b1f, mfma16(A2a[4], b0, zz4));
            _Float16* wp = s_B + (n * 16 + cc) * ROWLEN + 26 + 6 * q;
            f32x2 h01 = act_pair(z0, z1, c2p[n][0]);
            { f16x2 o; o.x = (_Float16)h01.x; o.y = (_Float16)h01.y; *(f16x2*)(wp) = o; }
            f32x2 h23 = act_pair(z2, z3, c2p[n][1]);
            { f16x2 o; o.x = (_Float16)h23.x; o.y = (_Float16)h23.y; *(f16x2*)(wp + 2) = o; }
            float h4 = act_one(z4, c2s[n]);
            wp[4] = (_Float16)h4;
        }

        x = xn;
    }

    // ---- head: relu(relu(h2 @ W1^T + b1) @ W2^T + b2), fp32 ----
    if (e < Btot) {
        const _Float16* rowp = s_B + lane * ROWLEN + 26;
        float hv[HH];
        #pragma unroll
        for (int qq = 0; qq < 4; ++qq)
            #pragma unroll
            for (int ww = 0; ww < 5; ++ww)
                hv[5 * qq + ww] = (float)rowp[6 * qq + ww];   // un-permute 6-stride

        float y2 = b2[0];
        #pragma unroll 1
        for (int jj = 0; jj < FF; ++jj) {
            float a = b1[jj];
            const float* __restrict__ wj = W1 + jj * HH;
            #pragma unroll
            for (int k = 0; k < HH; ++k)
                a = fmaf(hv[k], wj[k], a);
            a = fmaxf(a, 0.0f);
            y2 = fmaf(a, W2[jj], y2);
        }
        out[e] = fmaxf(y2, 0.0f);
    }
}

extern "C" void kernel_launch(void* const* d_in, const int* in_sizes, int n_in,
                              void* d_out, int out_size, void* d_ws, size_t ws_size,
                              hipStream_t stream)
{
    (void)n_in; (void)ws_size; (void)out_size;
    const float* diag = (const float*)d_in[0];
    const float* Wih1 = (const float*)d_in[1];
    const float* Whh1 = (const float*)d_in[2];
    const float* bih1 = (const float*)d_in[3];
    const float* bhh1 = (const float*)d_in[4];
    const float* Wih2 = (const float*)d_in[5];
    const float* Whh2 = (const float*)d_in[6];
    const float* bih2 = (const float*)d_in[7];
    const float* bhh2 = (const float*)d_in[8];
    const float* W1   = (const float*)d_in[9];
    const float* b1   = (const float*)d_in[10];
    const float* W2   = (const float*)d_in[11];
    const float* b2   = (const float*)d_in[12];

    const int Btot = in_sizes[0] / TSTEPS;   // 131072
    _Float16* wpk = (_Float16*)d_ws;

    prep_weights<<<8, 256, 0, stream>>>(Wih1, Whh1, bih1, bhh1,
                                        Wih2, Whh2, bih2, bhh2, wpk);

    lstm_mfma<<<(Btot + EPW - 1) / EPW, 64, 0, stream>>>(
        diag, wpk, W1, b1, W2, b2, (float*)d_out, Btot);
}

// Round 4
// 1276.751 us; speedup vs baseline: 7.4992x; 1.0316x over previous
//
#include <hip/hip_runtime.h>

#define HH 20
#define TSTEPS 256
#define FF 64
#define EPW 32             // batch elements per wave (1 wave per block)
#define NB 2               // n-blocks of 16 elements
#define ROWLEN 72          // f16 per LDS B-row; 144 B stride (16B-aligned)
#define LOG2E 1.44269504088896f
// B-row layout (f16 idx): [0..23] h1, 6-stride (lane q writes 6q..6q+4, 6q+5 pad)
//   [24]=x, [25]=1.0 (bias carrier), [26..49] h2 (same 6-stride), [50..71] zero

typedef __attribute__((ext_vector_type(8))) _Float16 f16x8;
typedef __attribute__((ext_vector_type(2))) _Float16 f16x2;
typedef __attribute__((ext_vector_type(4))) float    f32x4;
typedef __attribute__((ext_vector_type(2))) float    f32x2;

__device__ __forceinline__ f32x4 mfma16(f16x8 a, f16x8 b, f32x4 c) {
    return __builtin_amdgcn_mfma_f32_16x16x32_f16(a, b, c, 0, 0, 0);
}
__device__ __forceinline__ float rcpf(float x) { return __builtin_amdgcn_rcpf(x); }
__device__ __forceinline__ float exp2fast(float x) {
#if __has_builtin(__builtin_amdgcn_exp2f)
    return __builtin_amdgcn_exp2f(x);          // v_exp_f32: 2^x native
#else
    return __expf(x * 0.6931471805599453f);
#endif
}

// Gate quads arrive pre-scaled: si=-log2e*zi, sf=-log2e*zf, sg=2log2e*zg, so=-log2e*zo.
// 7-trans form: P=(1+ei)(1+eg), Q=(1+ef);  c' = (c*P + (eg-1)*Q) * rcp(P*Q)
//               h = (ec-1) * rcp((1+eo)(1+ec)),  ec = 2^min(2*log2e*c', 100)
__device__ __forceinline__ f32x2 act_pair(f32x4 za, f32x4 zb, f32x2& c) {
    f32x2 ei; ei.x = exp2fast(za.x); ei.y = exp2fast(zb.x);
    f32x2 ef; ef.x = exp2fast(za.y); ef.y = exp2fast(zb.y);
    f32x2 eg; eg.x = exp2fast(za.z); eg.y = exp2fast(zb.z);
    f32x2 eo; eo.x = exp2fast(za.w); eo.y = exp2fast(zb.w);
    const f32x2 one = {1.0f, 1.0f};
    f32x2 P = (one + ei) * (one + eg);
    f32x2 Q = one + ef;
    f32x2 num = c * P + (eg - one) * Q;
    f32x2 den = P * Q;
    f32x2 r; r.x = rcpf(den.x); r.y = rcpf(den.y);
    c = num * r;
    f32x2 sc = c * (2.0f * LOG2E);
    sc.x = fminf(sc.x, 100.0f); sc.y = fminf(sc.y, 100.0f);   // inf*0 NaN guard
    f32x2 ec; ec.x = exp2fast(sc.x); ec.y = exp2fast(sc.y);
    f32x2 den2 = (one + eo) * (one + ec);
    f32x2 r2; r2.x = rcpf(den2.x); r2.y = rcpf(den2.y);
    return (ec - one) * r2;
}
__device__ __forceinline__ float act_one(f32x4 za, float& c) {
    float ei = exp2fast(za.x), ef = exp2fast(za.y);
    float eg = exp2fast(za.z), eo = exp2fast(za.w);
    float P = (1.0f + ei) * (1.0f + eg);
    float Q = 1.0f + ef;
    float num = fmaf(c, P, (eg - 1.0f) * Q);
    c = num * rcpf(P * Q);
    float sc = fminf(c * (2.0f * LOG2E), 100.0f);
    float ec = exp2fast(sc);
    float r2 = rcpf((1.0f + eo) * (1.0f + ec));
    return (ec - 1.0f) * r2;
}

// ---------------------------------------------------------------------------
// Packed augmented weights, f16, PRE-SCALED by the exp2 gate factors.
// Matrix row r (0..79): m=r>>4, q=(r>>2)&3, g=r&3 -> unit u=5q+m, gate g
// (orig row ro = g*20+u). Column k follows the B-row layout above.
//   W1c [80][32] at ws[0..2559]; W2c [80][64] at ws[2560..7679].
// ---------------------------------------------------------------------------
__global__ void prep_weights(
    const float* __restrict__ Wih1, const float* __restrict__ Whh1,
    const float* __restrict__ bih1, const float* __restrict__ bhh1,
    const float* __restrict__ Wih2, const float* __restrict__ Whh2,
    const float* __restrict__ bih2, const float* __restrict__ bhh2,
    _Float16* __restrict__ ws)
{
    const int t0 = blockIdx.x * blockDim.x + threadIdx.x;
    const int stride = blockDim.x * gridDim.x;
    for (int idx = t0; idx < 80 * 32; idx += stride) {
        int r = idx >> 5, k = idx & 31;
        int m = r >> 4, q = (r >> 2) & 3, g = r & 3;
        int u = 5 * q + m, ro = g * HH + u;
        float s = (g == 2) ? 2.0f * LOG2E : -LOG2E;
        float v = 0.0f;
        if (k < 24)       { int qc = k / 6, wc = k % 6; if (wc < 5) v = Whh1[ro * HH + 5 * qc + wc]; }
        else if (k == 24)   v = Wih1[ro];
        else if (k == 25)   v = bih1[ro] + bhh1[ro];
        ws[idx] = (_Float16)(s * v);
    }
    for (int idx = t0; idx < 80 * 64; idx += stride) {
        int r = idx >> 6, k = idx & 63;
        int m = r >> 4, q = (r >> 2) & 3, g = r & 3;
        int u = 5 * q + m, ro = g * HH + u;
        float s = (g == 2) ? 2.0f * LOG2E : -LOG2E;
        float v = 0.0f;
        if (k < 24)       { int qc = k / 6, wc = k % 6; if (wc < 5) v = Wih2[ro * HH + 5 * qc + wc]; }
        else if (k == 25)   v = bih2[ro] + bhh2[ro];
        else if (k >= 26 && k < 50) {
            int cH = k - 26, qc = cH / 6, wc = cH % 6;
            if (wc < 5) v = Whh2[ro * HH + 5 * qc + wc];
        }
        ws[2560 + idx] = (_Float16)(s * v);
    }
}

// ---------------------------------------------------------------------------
// One wave per block, 32 elements per wave (4 waves/SIMD across the grid),
// weights stationary in VGPRs, c in VGPRs. Lane (q=lane>>4, cc=lane&15):
// owns units {5q..5q+4} for the two 16-element n-blocks.
// ---------------------------------------------------------------------------
__global__ __launch_bounds__(64, 4) void lstm_mfma(
    const float* __restrict__ diag,
    const _Float16* __restrict__ wpk,
    const float* __restrict__ W1, const float* __restrict__ b1,
    const float* __restrict__ W2, const float* __restrict__ b2,
    float* __restrict__ out, int Btot)
{
    __shared__ _Float16 s_B[EPW * ROWLEN];     // 4608 B

    const int lane = threadIdx.x;              // 0..63
    const int q  = lane >> 4;
    const int cc = lane & 15;
    const int e  = blockIdx.x * EPW + (lane & (EPW - 1));
    const int esafe = (e < Btot) ? e : (Btot - 1);

    // zero B-rows (one row per lane<32; 144 B = 9 x uint4)
    if (lane < EPW) {
        uint4 zz = {0u, 0u, 0u, 0u};
        #pragma unroll
        for (int j = 0; j < 9; ++j)
            *(uint4*)((char*)s_B + lane * 144 + j * 16) = zz;
    }

    // stationary A-fragments: lane supplies A[row=16m+cc][k=8q..8q+7]
    f16x8 A1[5], A2a[5], A2b[5];
    {
        const _Float16* W2c = wpk + 2560;
        const int kb = q * 8;
        #pragma unroll
        for (int m = 0; m < 5; ++m) {
            const int r = 16 * m + cc;
            A1[m]  = *(const f16x8*)(wpk + r * 32 + kb);
            A2a[m] = *(const f16x8*)(W2c + r * 64 + kb);
            A2b[m] = *(const f16x8*)(W2c + r * 64 + 32 + kb);
        }
    }

    // cell state: per n-block, 2 packed pairs + 1 scalar per layer
    f32x2 c1p[NB][2], c2p[NB][2];
    float c1s[NB], c2s[NB];
    #pragma unroll
    for (int n = 0; n < NB; ++n) {
        c1p[n][0] = (f32x2){0.0f, 0.0f}; c1p[n][1] = (f32x2){0.0f, 0.0f};
        c2p[n][0] = (f32x2){0.0f, 0.0f}; c2p[n][1] = (f32x2){0.0f, 0.0f};
        c1s[n] = 0.0f; c2s[n] = 0.0f;
    }

    const float* __restrict__ xr = diag + (long long)esafe * TSTEPS;
    float x = xr[0];
    const f32x4 zz4 = {0.0f, 0.0f, 0.0f, 0.0f};

    #pragma unroll 1
    for (int t = 0; t < TSTEPS; ++t) {
        float xn = xr[(t + 1) & (TSTEPS - 1)];   // prefetch (wraps; unused at end)

        // publish x(t) and the 1.0 bias carrier at k=24,25 of own row
        if (lane < EPW) {
            f16x2 pk; pk.x = (_Float16)x; pk.y = (_Float16)1.0f;
            *(f16x2*)(s_B + lane * ROWLEN + 24) = pk;
        }

        // ================= layer 1 =================
        #pragma unroll
        for (int n = 0; n < NB; ++n) {
            const _Float16* rowp = s_B + (n * 16 + cc) * ROWLEN;
            f16x8 bf = *(const f16x8*)(rowp + 8 * q);
            f32x4 z0 = mfma16(A1[0], bf, zz4);
            f32x4 z1 = mfma16(A1[1], bf, zz4);
            f32x4 z2 = mfma16(A1[2], bf, zz4);
            f32x4 z3 = mfma16(A1[3], bf, zz4);
            f32x4 z4 = mfma16(A1[4], bf, zz4);
            _Float16* wp = s_B + (n * 16 + cc) * ROWLEN + 6 * q;
            f32x2 h01 = act_pair(z0, z1, c1p[n][0]);
            { f16x2 o; o.x = (_Float16)h01.x; o.y = (_Float16)h01.y; *(f16x2*)(wp) = o; }
            f32x2 h23 = act_pair(z2, z3, c1p[n][1]);
            { f16x2 o; o.x = (_Float16)h23.x; o.y = (_Float16)h23.y; *(f16x2*)(wp + 2) = o; }
            float h4 = act_one(z4, c1s[n]);
            wp[4] = (_Float16)h4;
        }

        // ================= layer 2 =================
        #pragma unroll
        for (int n = 0; n < NB; ++n) {
            const _Float16* rowp = s_B + (n * 16 + cc) * ROWLEN;
            f16x8 b0  = *(const f16x8*)(rowp + 8 * q);        // k 0..31
            f16x8 b1f = *(const f16x8*)(rowp + 32 + 8 * q);   // k 32..63
            f32x4 z0 = mfma16(A2b[0], b1f, mfma16(A2a[0], b0, zz4));
            f32x4 z1 = mfma16(A2b[1], b1f, mfma16(A2a[1], b0, zz4));
            f32x4 z2 = mfma16(A2b[2], b1f, mfma16(A2a[2], b0, zz4));
            f32x4 z3 = mfma16(A2b[3], b1f, mfma16(A2a[3], b0, zz4));
            f32x4 z4 = mfma16(A2b[4], b1f, mfma16(A2a[4], b0, zz4));
            _Float16* wp = s_B + (n * 16 + cc) * ROWLEN + 26 + 6 * q;
            f32x2 h01 = act_pair(z0, z1, c2p[n][0]);
            { f16x2 o; o.x = (_Float16)h01.x; o.y = (_Float16)h01.y; *(f16x2*)(wp) = o; }
            f32x2 h23 = act_pair(z2, z3, c2p[n][1]);
            { f16x2 o; o.x = (_Float16)h23.x; o.y = (_Float16)h23.y; *(f16x2*)(wp + 2) = o; }
            float h4 = act_one(z4, c2s[n]);
            wp[4] = (_Float16)h4;
        }

        x = xn;
    }

    // ---- head: relu(relu(h2 @ W1^T + b1) @ W2^T + b2), fp32, lanes 0..31 ----
    if (lane < EPW && e < Btot) {
        const _Float16* rowp = s_B + lane * ROWLEN + 26;
        float hv[HH];
        #pragma unroll
        for (int qq = 0; qq < 4; ++qq)
            #pragma unroll
            for (int ww = 0; ww < 5; ++ww)
                hv[5 * qq + ww] = (float)rowp[6 * qq + ww];   // un-permute 6-stride

        float y2 = b2[0];
        #pragma unroll 1
        for (int jj = 0; jj < FF; ++jj) {
            float a = b1[jj];
            const float* __restrict__ wj = W1 + jj * HH;
            #pragma unroll
            for (int k = 0; k < HH; ++k)
                a = fmaf(hv[k], wj[k], a);
            a = fmaxf(a, 0.0f);
            y2 = fmaf(a, W2[jj], y2);
        }
        out[e] = fmaxf(y2, 0.0f);
    }
}

extern "C" void kernel_launch(void* const* d_in, const int* in_sizes, int n_in,
                              void* d_out, int out_size, void* d_ws, size_t ws_size,
                              hipStream_t stream)
{
    (void)n_in; (void)ws_size; (void)out_size;
    const float* diag = (const float*)d_in[0];
    const float* Wih1 = (const float*)d_in[1];
    const float* Whh1 = (const float*)d_in[2];
    const float* bih1 = (const float*)d_in[3];
    const float* bhh1 = (const float*)d_in[4];
    const float* Wih2 = (const float*)d_in[5];
    const float* Whh2 = (const float*)d_in[6];
    const float* bih2 = (const float*)d_in[7];
    const float* bhh2 = (const float*)d_in[8];
    const float* W1   = (const float*)d_in[9];
    const float* b1   = (const float*)d_in[10];
    const float* W2   = (const float*)d_in[11];
    const float* b2   = (const float*)d_in[12];

    const int Btot = in_sizes[0] / TSTEPS;   // 131072
    _Float16* wpk = (_Float16*)d_ws;

    prep_weights<<<8, 256, 0, stream>>>(Wih1, Whh1, bih1, bhh1,
                                        Wih2, Whh2, bih2, bhh2, wpk);

    lstm_mfma<<<(Btot + EPW - 1) / EPW, 64, 0, stream>>>(
        diag, wpk, W1, b1, W2, b2, (float*)d_out, Btot);
}